// Round 1
// baseline (159.569 us; speedup 1.0000x reference)
//
#include <hip/hip_runtime.h>

// BahdanauAttention_16518444220431 — diagonal-DP recurrence on MI355X (gfx950).
// Strategy: fully fused per-tile chains (no HBM intermediates), bf16 MFMA
// 32x32x16 computing U_new^T = W2 * U^T so writeback is ds_write_b64.
// a=W1x+b1+b2 rides as an extra K=16 MFMA step. W2 frags: half VGPR-cached,
// half streamed from L2 (pre-shuffled by prep kernel into d_ws).

typedef __bf16 bf16x8 __attribute__((ext_vector_type(8)));
typedef float f32x16 __attribute__((ext_vector_type(16)));

#define MFMA32(a, b, c) __builtin_amdgcn_mfma_f32_32x32x16_bf16(a, b, c, 0, 0, 0)

__device__ __forceinline__ unsigned short f2bf(float f) {
  unsigned int u = __builtin_bit_cast(unsigned int, f);
  u += 0x7fffu + ((u >> 16) & 1u);
  return (unsigned short)(u >> 16);
}
__device__ __forceinline__ float bf2f(unsigned short s) {
  unsigned int u = ((unsigned int)s) << 16;
  return __builtin_bit_cast(float, u);
}

// ws layout (bf16 elements):
//   [0,65536)        W2 fragments: ((ot*16+ks)*64+lane)*8+j ; o=ot*32+(lane&31), k=ks*16+(lane>>5)*8+j
//   [65536,131072)   W4 fragments, same permutation
//   [131072,135168)  W1-extra frags: lanes<32: j<4 -> W1[o][j], j==4 -> b1[o]+b2[o], else 0
//   [135168,139264)  W3-extra frags: j==4 -> b3[o]+2*b4[o]
__global__ void prep_kernel(const float* __restrict__ W1, const float* __restrict__ b1,
                            const float* __restrict__ W2, const float* __restrict__ b2,
                            const float* __restrict__ W3, const float* __restrict__ b3,
                            const float* __restrict__ W4, const float* __restrict__ b4,
                            unsigned short* __restrict__ ws) {
  int idx = blockIdx.x * 256 + threadIdx.x;
  if (idx >= 139264) return;
  float v = 0.0f;
  if (idx < 131072) {
    const float* W = (idx < 65536) ? W2 : W4;
    int i = idx & 65535;
    int j = i & 7, f = i >> 3;
    int lane = f & 63, slot = f >> 6;
    int ks = slot & 15, ot = slot >> 4;
    int o = ot * 32 + (lane & 31);
    int k = ks * 16 + (lane >> 5) * 8 + j;
    v = W[o * 256 + k];
  } else {
    int i = idx - 131072;
    bool first = (i < 4096);
    int ii = i & 4095;
    int j = ii & 7, f = ii >> 3;
    int lane = f & 63, ot = f >> 6;
    int o = ot * 32 + (lane & 31);
    if (lane < 32) {
      if (j < 4) v = first ? W1[o * 4 + j] : W3[o * 4 + j];
      else if (j == 4) v = first ? (b1[o] + b2[o]) : (b3[o] + 2.0f * b4[o]);
    }
  }
  ws[idx] = f2bf(v);
}

__global__ __launch_bounds__(256, 2)
void chain_kernel(const float* __restrict__ x, const unsigned short* __restrict__ ws,
                  float* __restrict__ out) {
  // U buffers: 64 rows x 32 16B-chunks (256 bf16/row), chunk column XOR-swizzled by (row&7)
  __shared__ int4 Ubuf[2][64 * 32];
  __shared__ int4 xw[80];   // [x0,x1,x2,x3,1,0,0,0] bf16 chunks for rows j0-8 .. j0+71
  __shared__ int4 zc;       // zero chunk for hi-lane extra-K reads

  const int tid = threadIdx.x;
  const int l = tid & 63;
  const int w = tid >> 6;
  const int lane31 = l & 31;
  const int khalf = l >> 5;
  const int b = blockIdx.x >> 5;
  const int j0 = (blockIdx.x & 31) * 64;

  const int4* w2f = (const int4*)ws;
  const int4* w4f = (const int4*)(ws + 65536);
  const int4* w1xg = (const int4*)(ws + 131072);
  const int4* w3xg = (const int4*)(ws + 135168);

  if (tid == 0) zc = make_int4(0, 0, 0, 0);
  if (tid < 80) {
    int j = j0 - 8 + tid;
    int4 c = make_int4(0, 0, 0, 0);
    if (j >= 0 && j < 2048) {
      const float* xb = x + (b * 4) * 2048 + j;
      unsigned short h0 = f2bf(xb[0]);
      unsigned short h1 = f2bf(xb[2048]);
      unsigned short h2 = f2bf(xb[4096]);
      unsigned short h3 = f2bf(xb[6144]);
      c = make_int4((int)(h0 | ((unsigned int)h1 << 16)),
                    (int)(h2 | ((unsigned int)h3 << 16)),
                    0x00003f80, 0);  // chunk[4] = bf16(1.0) -> multiplies the bias row
    }
    xw[tid] = c;
  }

  const int ot0 = w * 2;
  bf16x8 w2c[2][8];
  bf16x8 w1x[2];
#pragma unroll
  for (int t2 = 0; t2 < 2; ++t2) {
    w1x[t2] = __builtin_bit_cast(bf16x8, w1xg[(ot0 + t2) * 64 + l]);
#pragma unroll
    for (int ks = 0; ks < 8; ++ks)
      w2c[t2][ks] = __builtin_bit_cast(bf16x8, w2f[((ot0 + t2) * 16 + ks) * 64 + l]);
  }
  __syncthreads();

  const int mrow0 = lane31;
  const int mrow1 = 32 + lane31;

#pragma unroll 1
  for (int phase = 0; phase < 2; ++phase) {  // 0 = up chain, 1 = down chain
    int4* U = Ubuf[phase];
#pragma unroll 1
    for (int t = 1; t <= 8; ++t) {
      f32x16 acc[2][2] = {};
      // ---- extra K=16 step: adds a[idx] + bias (zero chunk at seq boundaries) ----
#pragma unroll
      for (int mt = 0; mt < 2; ++mt) {
        int m = mt ? mrow1 : mrow0;
        int widx = (phase == 0) ? (m + t - 1) : (m + 17 - t);
        const int4* p = (l < 32) ? (xw + widx) : (&zc);
        bf16x8 bx = __builtin_bit_cast(bf16x8, *p);
        acc[mt][0] = MFMA32(w1x[0], bx, acc[mt][0]);
        acc[mt][1] = MFMA32(w1x[1], bx, acc[mt][1]);
      }
      // ---- main GEMM over previous state (skip at t=1: state is zero) ----
      if (t > 1) {
#pragma unroll
        for (int ks = 0; ks < 16; ++ks) {
          int c0 = 2 * ks + khalf;
          bf16x8 bu0 = __builtin_bit_cast(bf16x8, U[mrow0 * 32 + (c0 ^ (mrow0 & 7))]);
          bf16x8 bu1 = __builtin_bit_cast(bf16x8, U[mrow1 * 32 + (c0 ^ (mrow1 & 7))]);
          bf16x8 af0, af1;
          if (ks < 8) { af0 = w2c[0][ks]; af1 = w2c[1][ks]; }
          else {
            af0 = __builtin_bit_cast(bf16x8, w2f[(ot0 * 16 + ks) * 64 + l]);
            af1 = __builtin_bit_cast(bf16x8, w2f[((ot0 + 1) * 16 + ks) * 64 + l]);
          }
          acc[0][0] = MFMA32(af0, bu0, acc[0][0]);
          acc[0][1] = MFMA32(af1, bu0, acc[0][1]);
          acc[1][0] = MFMA32(af0, bu1, acc[1][0]);
          acc[1][1] = MFMA32(af1, bu1, acc[1][1]);
        }
      }
      __syncthreads();
      // ---- relu + bf16 pack + swizzled writeback (C layout: col=m, row=o) ----
      const bool lastdown = (phase == 1) && (t == 8);
#pragma unroll
      for (int mt = 0; mt < 2; ++mt) {
        int row = mt ? mrow1 : mrow0;
#pragma unroll
        for (int t2 = 0; t2 < 2; ++t2) {
          int ot = ot0 + t2;
#pragma unroll
          for (int q = 0; q < 4; ++q) {
            float v0 = fmaxf(acc[mt][t2][4 * q + 0], 0.0f);
            float v1 = fmaxf(acc[mt][t2][4 * q + 1], 0.0f);
            float v2 = fmaxf(acc[mt][t2][4 * q + 2], 0.0f);
            float v3 = fmaxf(acc[mt][t2][4 * q + 3], 0.0f);
            int co = ot * 4 + q;
            int coff = row * 32 + (co ^ (row & 7));
            if (lastdown) {  // fuse s = relu(down) + up  (up already relu'd, in Ubuf[0])
              uint2 uv = *(const uint2*)((const char*)(Ubuf[0] + coff) + khalf * 8);
              v0 += bf2f((unsigned short)(uv.x & 0xffffu));
              v1 += bf2f((unsigned short)(uv.x >> 16));
              v2 += bf2f((unsigned short)(uv.y & 0xffffu));
              v3 += bf2f((unsigned short)(uv.y >> 16));
            }
            uint2 pk;
            pk.x = f2bf(v0) | ((unsigned int)f2bf(v1) << 16);
            pk.y = f2bf(v2) | ((unsigned int)f2bf(v3) << 16);
            *(uint2*)((char*)(U + coff) + khalf * 8) = pk;
          }
        }
      }
      __syncthreads();
    }
  }

  // ---- final: miu^T = relu(W3x + b3 + 2b4 + W4 * s) ----
  {
    f32x16 acc[2][2] = {};
    bf16x8 w3x0 = __builtin_bit_cast(bf16x8, w3xg[ot0 * 64 + l]);
    bf16x8 w3x1 = __builtin_bit_cast(bf16x8, w3xg[(ot0 + 1) * 64 + l]);
#pragma unroll
    for (int mt = 0; mt < 2; ++mt) {
      int m = mt ? mrow1 : mrow0;
      const int4* p = (l < 32) ? (xw + (m + 8)) : (&zc);
      bf16x8 bx = __builtin_bit_cast(bf16x8, *p);
      acc[mt][0] = MFMA32(w3x0, bx, acc[mt][0]);
      acc[mt][1] = MFMA32(w3x1, bx, acc[mt][1]);
    }
    const int4* S = Ubuf[1];
#pragma unroll
    for (int ks = 0; ks < 16; ++ks) {
      int c0 = 2 * ks + khalf;
      bf16x8 bu0 = __builtin_bit_cast(bf16x8, S[mrow0 * 32 + (c0 ^ (mrow0 & 7))]);
      bf16x8 bu1 = __builtin_bit_cast(bf16x8, S[mrow1 * 32 + (c0 ^ (mrow1 & 7))]);
      bf16x8 af0 = __builtin_bit_cast(bf16x8, w4f[(ot0 * 16 + ks) * 64 + l]);
      bf16x8 af1 = __builtin_bit_cast(bf16x8, w4f[((ot0 + 1) * 16 + ks) * 64 + l]);
      acc[0][0] = MFMA32(af0, bu0, acc[0][0]);
      acc[0][1] = MFMA32(af1, bu0, acc[0][1]);
      acc[1][0] = MFMA32(af0, bu1, acc[1][0]);
      acc[1][1] = MFMA32(af1, bu1, acc[1][1]);
    }
#pragma unroll
    for (int mt = 0; mt < 2; ++mt) {
      int m = mt ? mrow1 : mrow0;
      int pbase = (b * 2048 + j0 + m) * 256;
#pragma unroll
      for (int t2 = 0; t2 < 2; ++t2) {
#pragma unroll
        for (int q = 0; q < 4; ++q) {
          int ob = (ot0 + t2) * 32 + 8 * q + 4 * khalf;
          float4 v;
          v.x = fmaxf(acc[mt][t2][4 * q + 0], 0.0f);
          v.y = fmaxf(acc[mt][t2][4 * q + 1], 0.0f);
          v.z = fmaxf(acc[mt][t2][4 * q + 2], 0.0f);
          v.w = fmaxf(acc[mt][t2][4 * q + 3], 0.0f);
          *(float4*)(out + pbase + ob) = v;
        }
      }
    }
  }
}

extern "C" void kernel_launch(void* const* d_in, const int* in_sizes, int n_in,
                              void* d_out, int out_size, void* d_ws, size_t ws_size,
                              hipStream_t stream) {
  const float* x  = (const float*)d_in[0];
  const float* W1 = (const float*)d_in[1];
  const float* b1 = (const float*)d_in[2];
  const float* W2 = (const float*)d_in[3];
  const float* b2 = (const float*)d_in[4];
  const float* W3 = (const float*)d_in[5];
  const float* b3 = (const float*)d_in[6];
  const float* W4 = (const float*)d_in[7];
  const float* b4 = (const float*)d_in[8];
  unsigned short* ws = (unsigned short*)d_ws;

  prep_kernel<<<544, 256, 0, stream>>>(W1, b1, W2, b2, W3, b3, W4, b4, ws);
  chain_kernel<<<512, 256, 0, stream>>>(x, ws, (float*)d_out);
}